// Round 14
// baseline (232.552 us; speedup 1.0000x reference)
//
#include <hip/hip_runtime.h>
#include <hip/hip_bf16.h>

typedef unsigned int uint;
typedef unsigned short ushort;

#define N_NODES 50000
#define N_EDGES 800000
#define FDIM 128
#define HID 64
#define NPERM 128
#define HLLM 64
#define DUMMY 50000                // identity row index

#define BSHIFT 8
#define BNODES 256                 // nodes per bucket
#define NBUCK 196                  // ceil(50000/256)
#define CAPB 6144                  // fixed ebuf capacity/bucket (mean 4096, 32 sigma)
#define SCAT_BLOCKS 256
#define EDGES_PER_BLK 3125         // 800000/256 exactly
#define PACKMH_BLOCKS 12500        // 50000*64 uints / 256
#define MH16_BLOCKS 3125           // 16 nodes/block, 16 lanes/node
#define AGG16_BLOCKS 3125
#define HLL_BLOCKS 3125            // 16 nodes/block
#define SLICE_CAP 8448
#define CONV_BLOCKS 782            // ceil(50000/64)

__device__ __forceinline__ uint pk_min_u16(uint a, uint b) {
    uint d;
    asm("v_pk_min_u16 %0, %1, %2" : "=v"(d) : "v"(a), "v"(b));
    return d;
}
__device__ __forceinline__ uint4 pk_min4(uint4 a, uint4 b) {
    uint4 d;
    d.x = pk_min_u16(a.x, b.x); d.y = pk_min_u16(a.y, b.y);
    d.z = pk_min_u16(a.z, b.z); d.w = pk_min_u16(a.w, b.w);
    return d;
}

// ========== mh: 16 lanes/node (4 nodes/wave), uint4/lane covers packed uints [4q,4q+4) ==========

__device__ __forceinline__ void mh_body(int node, uint q, const int2* __restrict__ off2,
                                        const ushort* __restrict__ csr,
                                        const uint* __restrict__ mh_in,
                                        uint* __restrict__ out_p, float* __restrict__ out_f) {
    int2 se = off2[node];
    uint4 A = {0xFFFFFFFFu, 0xFFFFFFFFu, 0xFFFFFFFFu, 0xFFFFFFFFu};
    uint4 B = A;
    uint off = 4u * q;
    for (int p = se.x; p < se.y; p += 8) {
        uint4 c4 = *(const uint4*)(csr + p);
        uint j0 = c4.x & 0xFFFFu, j1 = c4.x >> 16;
        uint j2 = c4.y & 0xFFFFu, j3 = c4.y >> 16;
        uint j4 = c4.z & 0xFFFFu, j5 = c4.z >> 16;
        uint j6 = c4.w & 0xFFFFu, j7 = c4.w >> 16;
        uint4 a0 = *(const uint4*)(mh_in + j0 * 64u + off);
        uint4 a1 = *(const uint4*)(mh_in + j1 * 64u + off);
        uint4 a2 = *(const uint4*)(mh_in + j2 * 64u + off);
        uint4 a3 = *(const uint4*)(mh_in + j3 * 64u + off);
        uint4 a4 = *(const uint4*)(mh_in + j4 * 64u + off);
        uint4 a5 = *(const uint4*)(mh_in + j5 * 64u + off);
        uint4 a6 = *(const uint4*)(mh_in + j6 * 64u + off);
        uint4 a7 = *(const uint4*)(mh_in + j7 * 64u + off);
        A = pk_min4(A, a0); B = pk_min4(B, a1);
        A = pk_min4(A, a2); B = pk_min4(B, a3);
        A = pk_min4(A, a4); B = pk_min4(B, a5);
        A = pk_min4(A, a6); B = pk_min4(B, a7);
    }
    uint4 M = pk_min4(A, B);
    if (out_p) {
        *(uint4*)(out_p + (size_t)node * 64 + off) = M;
    } else {
        float4 w0, w1;
        w0.x = __uint_as_float((M.x & 0xFFFFu) << 16); w0.y = __uint_as_float(M.x & 0xFFFF0000u);
        w0.z = __uint_as_float((M.y & 0xFFFFu) << 16); w0.w = __uint_as_float(M.y & 0xFFFF0000u);
        w1.x = __uint_as_float((M.z & 0xFFFFu) << 16); w1.y = __uint_as_float(M.z & 0xFFFF0000u);
        w1.z = __uint_as_float((M.w & 0xFFFFu) << 16); w1.w = __uint_as_float(M.w & 0xFFFF0000u);
        float* o = out_f + (size_t)node * NPERM + 8u * q;
        *(float4*)o = w0;
        *(float4*)(o + 4) = w1;
    }
}

// ========== hll: 16 lanes/node, uint/lane ==========

__device__ __forceinline__ void hll_body(int node, uint q, const int2* __restrict__ off2,
                                         const ushort* __restrict__ csr,
                                         const uint* __restrict__ hll_in,
                                         uint* __restrict__ out_p, float* __restrict__ out_f,
                                         float* __restrict__ cards, int kcol) {
    int2 se = off2[node];
    uint m0 = 0, m1 = 0, m2 = 0, m3 = 0;
#define HLL_ACC(vv) do { uint _v = (vv); \
        m0 = max(m0, _v & 0xFFu); m1 = max(m1, (_v >> 8) & 0xFFu); \
        m2 = max(m2, (_v >> 16) & 0xFFu); m3 = max(m3, _v >> 24); } while (0)
#pragma unroll 2
    for (int p = se.x; p < se.y; p += 8) {
        uint4 c4 = *(const uint4*)(csr + p);
        uint j0 = c4.x & 0xFFFFu, j1 = c4.x >> 16;
        uint j2 = c4.y & 0xFFFFu, j3 = c4.y >> 16;
        uint j4 = c4.z & 0xFFFFu, j5 = c4.z >> 16;
        uint j6 = c4.w & 0xFFFFu, j7 = c4.w >> 16;
        uint a0 = hll_in[j0 * 16u + q];
        uint a1 = hll_in[j1 * 16u + q];
        uint a2 = hll_in[j2 * 16u + q];
        uint a3 = hll_in[j3 * 16u + q];
        uint a4 = hll_in[j4 * 16u + q];
        uint a5 = hll_in[j5 * 16u + q];
        uint a6 = hll_in[j6 * 16u + q];
        uint a7 = hll_in[j7 * 16u + q];
        HLL_ACC(a0); HLL_ACC(a1); HLL_ACC(a2); HLL_ACC(a3);
        HLL_ACC(a4); HLL_ACC(a5); HLL_ACC(a6); HLL_ACC(a7);
    }
#undef HLL_ACC
    if (out_p) out_p[(size_t)node * 16 + q] = m0 | (m1 << 8) | (m2 << 16) | (m3 << 24);
    if (out_f) {
        float4 w = {(float)m0, (float)m1, (float)m2, (float)m3};
        *(float4*)(out_f + (size_t)node * HLLM + 4 * q) = w;
    }
    float v = exp2f(-(float)m0) + exp2f(-(float)m1) + exp2f(-(float)m2) + exp2f(-(float)m3);
    v += __shfl_xor(v, 1); v += __shfl_xor(v, 2);
    v += __shfl_xor(v, 4); v += __shfl_xor(v, 8);
    if (q == 0) {
        const float alphamm = (float)(0.7213 / (1.0 + 1.079 / 64.0) * 64.0 * 64.0);
        cards[(size_t)node * 2 + kcol] = alphamm / v;
    }
}

// ========== agg: 16 lanes/node, uint2/lane = channels [4q,4q+4) ==========

__device__ __forceinline__ void agg_body(int node, uint q, const int2* __restrict__ off2,
                                         const ushort* __restrict__ csr,
                                         const uint* __restrict__ hWs32,
                                         const float* __restrict__ dis,
                                         const float* __restrict__ b,
                                         const float* __restrict__ h_in,
                                         float* __restrict__ h_out) {
    int2 se = off2[node];
    float s0 = 0.f, s1 = 0.f, s2 = 0.f, s3 = 0.f;
    uint off = 2u * q;
#define AGG_ACC(aa) do { uint2 _a = (aa); \
        s0 += __uint_as_float(_a.x << 16); s1 += __uint_as_float(_a.x & 0xFFFF0000u); \
        s2 += __uint_as_float(_a.y << 16); s3 += __uint_as_float(_a.y & 0xFFFF0000u); } while (0)
    for (int p = se.x; p < se.y; p += 8) {
        uint4 c4 = *(const uint4*)(csr + p);
        uint j0 = c4.x & 0xFFFFu, j1 = c4.x >> 16;
        uint j2 = c4.y & 0xFFFFu, j3 = c4.y >> 16;
        uint j4 = c4.z & 0xFFFFu, j5 = c4.z >> 16;
        uint j6 = c4.w & 0xFFFFu, j7 = c4.w >> 16;
        uint2 a0 = *(const uint2*)(hWs32 + j0 * 32u + off);
        uint2 a1 = *(const uint2*)(hWs32 + j1 * 32u + off);
        uint2 a2 = *(const uint2*)(hWs32 + j2 * 32u + off);
        uint2 a3 = *(const uint2*)(hWs32 + j3 * 32u + off);
        uint2 a4 = *(const uint2*)(hWs32 + j4 * 32u + off);
        uint2 a5 = *(const uint2*)(hWs32 + j5 * 32u + off);
        uint2 a6 = *(const uint2*)(hWs32 + j6 * 32u + off);
        uint2 a7 = *(const uint2*)(hWs32 + j7 * 32u + off);
        AGG_ACC(a0); AGG_ACC(a1); AGG_ACC(a2); AGG_ACC(a3);
        AGG_ACC(a4); AGG_ACC(a5); AGG_ACC(a6); AGG_ACC(a7);
    }
#undef AGG_ACC
    uint ch = 4u * q;
    size_t idx = (size_t)node * HID + ch;
    float4 hi = *(const float4*)(h_in + idx);
    float4 bb = *(const float4*)(b + ch);
    float d = dis[node];
    float4 o;
    o.x = hi.x + bb.x + d * s0;
    o.y = hi.y + bb.y + d * s1;
    o.z = hi.z + bb.z + d * s2;
    o.w = hi.w + bb.w + d * s3;
    *(float4*)(h_out + idx) = o;
}

// conv body with W from LDS (used by standalone k_conv)
__device__ __forceinline__ void convmm_body(int row, int c0, const float* __restrict__ h,
                                            const float* __restrict__ Ws,
                                            const float* __restrict__ dis,
                                            ushort* __restrict__ hWs) {
    float acc[16] = {0.f, 0.f, 0.f, 0.f, 0.f, 0.f, 0.f, 0.f,
                     0.f, 0.f, 0.f, 0.f, 0.f, 0.f, 0.f, 0.f};
    const float4* hr = (const float4*)(h + (size_t)row * HID);
    for (int k4 = 0; k4 < HID / 4; ++k4) {
        float4 hv = hr[k4];
        const float* wr = Ws + (k4 * 4) * HID + c0;
#pragma unroll
        for (int j = 0; j < 16; ++j) acc[j] = fmaf(hv.x, wr[j], acc[j]);
#pragma unroll
        for (int j = 0; j < 16; ++j) acc[j] = fmaf(hv.y, wr[HID + j], acc[j]);
#pragma unroll
        for (int j = 0; j < 16; ++j) acc[j] = fmaf(hv.z, wr[2 * HID + j], acc[j]);
#pragma unroll
        for (int j = 0; j < 16; ++j) acc[j] = fmaf(hv.w, wr[3 * HID + j], acc[j]);
    }
    float d = dis[row];
    ushort* o = hWs + (size_t)row * HID + c0;
#pragma unroll
    for (int j = 0; j < 16; ++j) {
        __hip_bfloat16 t = __float2bfloat16(d * acc[j]);
        o[j] = *(ushort*)&t;
    }
}

// ================= k_front: scatter | pack mh | pack hll | dummy init =================

__global__ void __launch_bounds__(256) k_front(const int* __restrict__ src,
                       const int* __restrict__ dst, int* __restrict__ gcur,
                       uint* __restrict__ ebuf,
                       const int* __restrict__ mh, uint* __restrict__ mhp,
                       uint* __restrict__ mhA,
                       const int* __restrict__ hll, uint* __restrict__ hp,
                       uint* __restrict__ hllA) {
    __shared__ uint ecache[EDGES_PER_BLK];
    __shared__ int cnt[NBUCK];
    __shared__ int cur[NBUCK];
    int b = blockIdx.x;
    int t = threadIdx.x;
    if (b < SCAT_BLOCKS) {
        for (int i = t; i < NBUCK; i += 256) cnt[i] = 0;
        __syncthreads();
        int e0 = b * EDGES_PER_BLK;
        for (int i = t; i < EDGES_PER_BLK; i += 256) {
            int d = dst[e0 + i];
            int s = src[e0 + i];
            ecache[i] = ((uint)s << 16) | (uint)d;   // both < 65536
            atomicAdd(&cnt[d >> BSHIFT], 1);
        }
        __syncthreads();
        for (int bb = t; bb < NBUCK; bb += 256)
            cur[bb] = bb * CAPB + atomicAdd(&gcur[bb], cnt[bb]);
        __syncthreads();
        for (int i = t; i < EDGES_PER_BLK; i += 256) {
            uint en = ecache[i];
            uint d = en & 0xFFFFu;
            int p = atomicAdd(&cur[d >> BSHIFT], 1);
            ebuf[p] = ((en >> 16) << BSHIFT) | (d & (BNODES - 1));
        }
    } else if (b < SCAT_BLOCKS + PACKMH_BLOCKS) {
        int i = (b - SCAT_BLOCKS) * 256 + t;
        int2 v = ((const int2*)mh)[i];
        uint u0 = __float_as_uint((float)v.x) >> 16;
        uint u1 = __float_as_uint((float)v.y) >> 16;
        mhp[i] = u0 | (u1 << 16);
    } else if (b < SCAT_BLOCKS + PACKMH_BLOCKS + HLL_BLOCKS) {
        int i = (b - SCAT_BLOCKS - PACKMH_BLOCKS) * 256 + t;
        int4 v = ((const int4*)hll)[i];
        hp[i] = (uint)v.x | ((uint)v.y << 8) | ((uint)v.z << 16) | ((uint)v.w << 24);
    } else {
        if (t < 64) {
            mhp[(size_t)DUMMY * 64 + t] = 0xFFFFFFFFu;
            mhA[(size_t)DUMMY * 64 + t] = 0xFFFFFFFFu;
        } else if (t < 80) {
            hp[(size_t)DUMMY * 16 + (t - 64)] = 0u;
        } else if (t < 96) {
            hllA[(size_t)DUMMY * 16 + (t - 80)] = 0u;
        }
    }
}

// ================= k_fat1: csr | encoder =================

__global__ void __launch_bounds__(256) k_fat1(const uint* __restrict__ ebuf,
                      const int* __restrict__ gcur, int* __restrict__ pcur,
                      int2* __restrict__ off2, float* __restrict__ dis,
                      ushort* __restrict__ csr,
                      const float* __restrict__ x, const float* __restrict__ W_enc,
                      const float* __restrict__ b_enc, float* __restrict__ h) {
    __shared__ uint smem[SLICE_CAP + BNODES + 256 + 1];   // ~35.8 KB
    int b = blockIdx.x;
    int t = threadIdx.x;
    if (b < NBUCK) {
        uint* slice = smem;
        int* lcur = (int*)(smem + SLICE_CAP);
        int* ssum = (int*)(smem + SLICE_CAP + BNODES);
        int* sbase = (int*)(smem + SLICE_CAP + BNODES + 256);
        int lo = b << BSHIFT;
        int nbkt = min(BNODES, N_NODES - lo);
        int ebase = b * CAPB;
        int ecnt = gcur[b];
        lcur[t] = 0;
        __syncthreads();
        for (int i = t; i < ecnt; i += 256)
            atomicAdd(&lcur[ebuf[ebase + i] & (BNODES - 1)], 1);
        __syncthreads();
        int a0 = lcur[t];                      // in-degree (excl self)
        int plen = (t < nbkt) ? ((a0 + 8) & ~7) : 0;   // padded length incl self
        ssum[t] = plen;
        __syncthreads();
        for (int off = 1; off < 256; off <<= 1) {
            int u = (t >= off) ? ssum[t - off] : 0;
            __syncthreads();
            ssum[t] += u;
            __syncthreads();
        }
        int ppre = ssum[t] - plen;
        if (t == 255) sbase[0] = atomicAdd(pcur, ssum[255]);
        __syncthreads();
        int base = sbase[0];
        if (t < nbkt) {
            slice[ppre] = (uint)(lo + t);      // self-loop first
            lcur[t] = ppre + 1;
            off2[lo + t] = make_int2(base + ppre, base + ppre + plen);
            dis[lo + t] = rsqrtf((float)(a0 + 1));
        }
        __syncthreads();
        for (int i = t; i < ecnt; i += 256) {
            uint en = ebuf[ebase + i];
            int p = atomicAdd(&lcur[en & (BNODES - 1)], 1);
            slice[p] = en >> BSHIFT;
        }
        __syncthreads();
        if (t < nbkt)
            for (int i = lcur[t]; i < ppre + plen; ++i) slice[i] = DUMMY;
        __syncthreads();
        int total = ssum[255];
        for (int i = t; i < total; i += 256) csr[base + i] = (ushort)slice[i];
    } else {
        float* Ws = (float*)smem;
        for (int idx = t; idx < FDIM * HID; idx += 256) Ws[idx] = W_enc[idx];
        __syncthreads();
        int row = (b - NBUCK) * 64 + (t >> 2);
        int c0 = (t & 3) * 16;
        if (row >= N_NODES) return;
        float acc[16];
#pragma unroll
        for (int j = 0; j < 16; ++j) acc[j] = b_enc[c0 + j];
        const float4* xr = (const float4*)(x + (size_t)row * FDIM);
        for (int k4 = 0; k4 < FDIM / 4; ++k4) {
            float4 xv = xr[k4];
            const float* wr = Ws + (k4 * 4) * HID + c0;
#pragma unroll
            for (int j = 0; j < 16; ++j) acc[j] = fmaf(xv.x, wr[j], acc[j]);
#pragma unroll
            for (int j = 0; j < 16; ++j) acc[j] = fmaf(xv.y, wr[HID + j], acc[j]);
#pragma unroll
            for (int j = 0; j < 16; ++j) acc[j] = fmaf(xv.z, wr[2 * HID + j], acc[j]);
#pragma unroll
            for (int j = 0; j < 16; ++j) acc[j] = fmaf(xv.w, wr[3 * HID + j], acc[j]);
        }
        float* hr = h + (size_t)row * HID + c0;
#pragma unroll
        for (int j = 0; j < 16; ++j) hr[j] = acc[j];
    }
}

// ================= D1: mh0 | hll0 | conv0 (no LDS: conv reads W via L1) =================

__global__ void __launch_bounds__(256) k_hopA(const int2* __restrict__ off2,
                    const ushort* __restrict__ csr,
                    const uint* __restrict__ mh_in, uint* __restrict__ mh_out_p,
                    const uint* __restrict__ hll_in, uint* __restrict__ hll_out_p,
                    float* __restrict__ cards,
                    const float* __restrict__ h, const float* __restrict__ W,
                    const float* __restrict__ dis, ushort* __restrict__ hWs) {
    int blk = blockIdx.x;
    int t = threadIdx.x;
    if (blk < MH16_BLOCKS) {
        int node = blk * 16 + (t >> 4);
        mh_body(node, t & 15, off2, csr, mh_in, mh_out_p, nullptr);
    } else if (blk < MH16_BLOCKS + HLL_BLOCKS) {
        int node = (blk - MH16_BLOCKS) * 16 + (t >> 4);
        hll_body(node, t & 15, off2, csr, hll_in, hll_out_p, nullptr, cards, 0);
    } else {
        int row = (blk - MH16_BLOCKS - HLL_BLOCKS) * 64 + (t >> 2);
        int c0 = (t & 3) * 16;
        if (row > N_NODES) return;
        if (row == N_NODES) {           // dummy zero row
            ushort* o = hWs + (size_t)row * HID + c0;
#pragma unroll
            for (int j = 0; j < 16; ++j) o[j] = 0;
            return;
        }
        convmm_body(row, c0, h, W, dis, hWs);   // W from global (L1-hot, 16 KB shared)
    }
}

// ================= D2: mh1 | agg0 | hll1 =================

__global__ void __launch_bounds__(256) k_hopB(const int2* __restrict__ off2,
                    const ushort* __restrict__ csr,
                    const uint* __restrict__ mh_in, float* __restrict__ mh_out_f,
                    const uint* __restrict__ hWs32, const float* __restrict__ b0,
                    float* __restrict__ h_cur,
                    const uint* __restrict__ hll_in, float* __restrict__ hll_out_f,
                    float* __restrict__ cards, const float* __restrict__ dis) {
    int blk = blockIdx.x;
    int t = threadIdx.x;
    if (blk < MH16_BLOCKS) {
        int node = blk * 16 + (t >> 4);
        mh_body(node, t & 15, off2, csr, mh_in, nullptr, mh_out_f);
    } else if (blk < MH16_BLOCKS + AGG16_BLOCKS) {
        int node = (blk - MH16_BLOCKS) * 16 + (t >> 4);
        agg_body(node, t & 15, off2, csr, hWs32, dis, b0, h_cur, h_cur);
    } else {
        int node = (blk - MH16_BLOCKS - AGG16_BLOCKS) * 16 + (t >> 4);
        hll_body(node, t & 15, off2, csr, hll_in, nullptr, hll_out_f, cards, 1);
    }
}

// ================= D3: conv1 =================

__global__ void __launch_bounds__(256) k_conv(const float* __restrict__ h,
                         const float* __restrict__ W, const float* __restrict__ dis,
                         ushort* __restrict__ hWs) {
    __shared__ float Ws[HID * HID];
    for (int i = threadIdx.x; i < HID * HID; i += 256) Ws[i] = W[i];
    __syncthreads();
    int row = blockIdx.x * 64 + (threadIdx.x >> 2);
    int c0 = (threadIdx.x & 3) * 16;
    if (row > N_NODES) return;
    if (row == N_NODES) {
        ushort* o = hWs + (size_t)row * HID + c0;
#pragma unroll
        for (int j = 0; j < 16; ++j) o[j] = 0;
        return;
    }
    convmm_body(row, c0, h, Ws, dis, hWs);
}

// ================= D4: agg1 -> out_h =================

__global__ void __launch_bounds__(256) k_agg(const int2* __restrict__ off2,
                      const ushort* __restrict__ csr, const uint* __restrict__ hWs32,
                      const float* __restrict__ dis, const float* __restrict__ b,
                      const float* __restrict__ h_in, float* __restrict__ h_out) {
    int t = threadIdx.x;
    int node = blockIdx.x * 16 + (t >> 4);
    agg_body(node, t & 15, off2, csr, hWs32, dis, b, h_in, h_out);
}

// ---------------- driver ----------------

static inline char* align256(char* p) {
    return (char*)(((uintptr_t)p + 255) & ~(uintptr_t)255);
}

extern "C" void kernel_launch(void* const* d_in, const int* in_sizes, int n_in,
                              void* d_out, int out_size, void* d_ws, size_t ws_size,
                              hipStream_t stream) {
    const float* x       = (const float*)d_in[0];
    const int*   ei      = (const int*)d_in[1];
    const int*   mh0     = (const int*)d_in[2];
    const int*   hll0    = (const int*)d_in[3];
    const float* W_enc   = (const float*)d_in[4];
    const float* b_enc   = (const float*)d_in[5];
    const float* W_convs = (const float*)d_in[6];
    const float* b_convs = (const float*)d_in[7];

    float* out       = (float*)d_out;
    float* out_h     = out;
    float* out_cards = out + (size_t)N_NODES * HID;
    float* out_mh    = out_cards + (size_t)N_NODES * 2;
    float* out_hll   = out_mh + (size_t)N_NODES * NPERM;

    char* w = (char*)d_ws;
    int*   gcur    = (int*)w;   w += (size_t)NBUCK * 4;
    int*   pcur    = (int*)w;   w = align256(w + 4);
    int2*  off2    = (int2*)w;  w = align256(w + (size_t)N_NODES * 8);
    float* dis     = (float*)w; w = align256(w + (size_t)N_NODES * 4);
    ushort* csr    = (ushort*)w; w = align256(w + (size_t)(N_EDGES + 8 * N_NODES) * 2);
    uint*  mhp0    = (uint*)w;  w = align256(w + (size_t)(N_NODES + 1) * 64 * 4);
    uint*  mhA     = (uint*)w;  w = align256(w + (size_t)(N_NODES + 1) * 64 * 4);
    uint*  hp0     = (uint*)w;  w = align256(w + (size_t)(N_NODES + 1) * 16 * 4);
    uint*  hllA    = (uint*)w;  w = align256(w + (size_t)(N_NODES + 1) * 16 * 4);
    float* h_cur   = (float*)w; w = align256(w + (size_t)N_NODES * HID * 4);
    ushort* hWs    = (ushort*)w; w = align256(w + (size_t)(N_NODES + 1) * HID * 2);
    uint*  ebuf    = mhA;  // build-phase alias (196*6144 uints = 4.8MB < 12.8MB extent);
                           // dummy row at 12.8MB offset untouched by ebuf

    const int* src = ei;
    const int* dst = ei + N_EDGES;

    // zero gcur (+pcur, adjacent) -> fixed bucket bases added in-kernel
    hipMemsetAsync(gcur, 0, (size_t)(NBUCK + 1) * 4, stream);
    // F1: scatter | pack mh | pack hll | dummy init
    k_front<<<SCAT_BLOCKS + PACKMH_BLOCKS + HLL_BLOCKS + 1, 256, 0, stream>>>(
        src, dst, gcur, ebuf, mh0, mhp0, mhA, hll0, hp0, hllA);
    // F2: csr | encoder
    k_fat1<<<NBUCK + CONV_BLOCKS, 256, 0, stream>>>(
        ebuf, gcur, pcur, off2, dis, csr, x, W_enc, b_enc, h_cur);

    // D1: mh0 | hll0 | conv0
    k_hopA<<<MH16_BLOCKS + HLL_BLOCKS + CONV_BLOCKS + 1, 256, 0, stream>>>(
        off2, csr, mhp0, mhA, hp0, hllA, out_cards, h_cur, W_convs, dis, hWs);
    // D2: mh1 | agg0 | hll1
    k_hopB<<<MH16_BLOCKS + AGG16_BLOCKS + HLL_BLOCKS, 256, 0, stream>>>(
        off2, csr, mhA, out_mh, (const uint*)hWs, b_convs, h_cur, hllA, out_hll, out_cards, dis);
    // D3: conv1
    k_conv<<<CONV_BLOCKS + 1, 256, 0, stream>>>(h_cur, W_convs + HID * HID, dis, hWs);
    // D4: agg1 -> out_h
    k_agg<<<AGG16_BLOCKS, 256, 0, stream>>>(off2, csr, (const uint*)hWs, dis, b_convs + HID, h_cur, out_h);
}